// Round 1
// baseline (11161.205 us; speedup 1.0000x reference)
//
#include <hip/hip_runtime.h>
#include <math.h>

#define CC 256
#define HH 64
#define WW 64
#define NN 4096
#define BB 4

// ---------------------------------------------------------------------------
// 3x3 SAME conv + bias + ReLU.  One thread per output element.
// Block 256 = 4 output channels x 64 x-positions (lane = x -> coalesced x
// reads, wave-uniform weight reads).  transposed=1 writes out[b][n][c]
// (for attention), transposed=0 writes out[b][c][h][w].
// ---------------------------------------------------------------------------
__global__ __launch_bounds__(256) void conv3_k(
    const float* __restrict__ x, const float* __restrict__ w,
    const float* __restrict__ bias, float* __restrict__ out,
    int transposed)
{
  int tid = threadIdx.x;
  int xx  = tid & 63;
  int cg  = blockIdx.x & 63;
  int y   = (blockIdx.x >> 6) & 63;
  int b   = blockIdx.x >> 12;
  int c   = (cg << 2) + (tid >> 6);

  float acc = bias[c];
  const float* xb = x + (size_t)b * CC * HH * WW;
  const float* wb = w + (size_t)c * CC * 9;

  for (int ci = 0; ci < CC; ++ci) {
    const float* xc = xb + (size_t)ci * HH * WW;
    const float* wc = wb + ci * 9;
#pragma unroll
    for (int ky = 0; ky < 3; ++ky) {
      int row = y + ky - 1;
      if ((unsigned)row < (unsigned)HH) {
        const float* xr = xc + row * WW;
        float w0 = wc[ky * 3 + 0];
        float w1 = wc[ky * 3 + 1];
        float w2 = wc[ky * 3 + 2];
        float xm = (xx > 0)      ? xr[xx - 1] : 0.f;
        float x0 = xr[xx];
        float xp = (xx < WW - 1) ? xr[xx + 1] : 0.f;
        acc = fmaf(xm, w0, acc);
        acc = fmaf(x0, w1, acc);
        acc = fmaf(xp, w2, acc);
      }
    }
  }
  acc = fmaxf(acc, 0.f);
  if (transposed)
    out[((size_t)b * NN + (y * WW + xx)) * CC + c] = acc;
  else
    out[(((size_t)b * CC + c) * HH + y) * WW + xx] = acc;
}

// ---------------------------------------------------------------------------
// Flash-style attention, fp32.  Block = (batch b, 64-query tile).
// qT/kT/vT: [B][N][C].  Writes ctx[b][c][n] = 2 * sum_m softmax(QK^T)[n,m] V.
// Thread grid 16x16: tq = tid>>4 owns queries tq*4..+3.
//   scores phase: tk = tid&15 owns keys  tk*2, tk*2+1 (of 32-key chunk)
//   PV phase:     tk selects channels {tk*4 + 64j + 0..3 : j=0..3}
// ---------------------------------------------------------------------------
__global__ __launch_bounds__(256) void attn_k(
    const float* __restrict__ qT, const float* __restrict__ kT,
    const float* __restrict__ vT, float* __restrict__ ctx)
{
  __shared__ float Qs[64][260];
  __shared__ float Ks[32][260];
  __shared__ float Vs[32][260];
  __shared__ float Ps[64][36];

  int tid = threadIdx.x;
  int b   = blockIdx.x >> 6;
  int q0  = (blockIdx.x & 63) << 6;
  int tq  = tid >> 4;
  int tk  = tid & 15;

  const float* qTb = qT + ((size_t)b * NN + q0) * CC;

  // stage Q tile [64][256]
  for (int i = tid; i < 64 * 64; i += 256) {
    int r = i >> 6, col = i & 63;
    float4 v = ((const float4*)qTb)[i];
    *(float4*)&Qs[r][col * 4] = v;
  }

  float m[4], l[4];
  float4 o[4][4];
#pragma unroll
  for (int i = 0; i < 4; ++i) {
    m[i] = -INFINITY;
    l[i] = 0.f;
#pragma unroll
    for (int j = 0; j < 4; ++j) o[i][j] = make_float4(0.f, 0.f, 0.f, 0.f);
  }

  for (int ch = 0; ch < NN / 32; ++ch) {
    __syncthreads();  // prev PV done (also covers Q staging on first iter)
    const float* kTb = kT + ((size_t)b * NN + ch * 32) * CC;
    const float* vTb = vT + ((size_t)b * NN + ch * 32) * CC;
    for (int i = tid; i < 32 * 64; i += 256) {
      int r = i >> 6, col = i & 63;
      *(float4*)&Ks[r][col * 4] = ((const float4*)kTb)[i];
      *(float4*)&Vs[r][col * 4] = ((const float4*)vTb)[i];
    }
    __syncthreads();

    // ---- scores: s[4 queries][2 keys], dot over 256 channels ----
    float s[4][2] = {{0.f,0.f},{0.f,0.f},{0.f,0.f},{0.f,0.f}};
    int k0 = tk * 2;
    for (int cb = 0; cb < 64; ++cb) {
      float4 kv0 = *(const float4*)&Ks[k0][cb * 4];
      float4 kv1 = *(const float4*)&Ks[k0 + 1][cb * 4];
#pragma unroll
      for (int i = 0; i < 4; ++i) {
        float4 qv = *(const float4*)&Qs[tq * 4 + i][cb * 4];
        s[i][0] += qv.x*kv0.x + qv.y*kv0.y + qv.z*kv0.z + qv.w*kv0.w;
        s[i][1] += qv.x*kv1.x + qv.y*kv1.y + qv.z*kv1.z + qv.w*kv1.w;
      }
    }

    // ---- online softmax update (row reduce over the 16 tk lanes) ----
#pragma unroll
    for (int i = 0; i < 4; ++i) {
      float cmax = fmaxf(s[i][0], s[i][1]);
      for (int off = 1; off < 16; off <<= 1)
        cmax = fmaxf(cmax, __shfl_xor(cmax, off));
      float mnew = fmaxf(m[i], cmax);
      float sc   = __expf(m[i] - mnew);   // m=-inf first chunk -> 0
      float p0   = __expf(s[i][0] - mnew);
      float p1   = __expf(s[i][1] - mnew);
      float ps   = p0 + p1;
      for (int off = 1; off < 16; off <<= 1)
        ps += __shfl_xor(ps, off);
      l[i] = l[i] * sc + ps;
      m[i] = mnew;
      Ps[tq * 4 + i][k0]     = p0;
      Ps[tq * 4 + i][k0 + 1] = p1;
#pragma unroll
      for (int j = 0; j < 4; ++j) {
        o[i][j].x *= sc; o[i][j].y *= sc; o[i][j].z *= sc; o[i][j].w *= sc;
      }
    }
    __syncthreads();  // Ps visible to all

    // ---- PV: o[q][cgroup] += P[q][k] * V[k][c] ----
#pragma unroll
    for (int k4 = 0; k4 < 8; ++k4) {
      float4 p[4];
#pragma unroll
      for (int i = 0; i < 4; ++i)
        p[i] = *(const float4*)&Ps[tq * 4 + i][k4 * 4];
#pragma unroll
      for (int kk = 0; kk < 4; ++kk) {
        int k = k4 * 4 + kk;
        float4 vv[4];
#pragma unroll
        for (int j = 0; j < 4; ++j)
          vv[j] = *(const float4*)&Vs[k][tk * 4 + j * 64];
#pragma unroll
        for (int i = 0; i < 4; ++i) {
          float pik = (kk == 0) ? p[i].x : (kk == 1) ? p[i].y
                    : (kk == 2) ? p[i].z : p[i].w;
#pragma unroll
          for (int j = 0; j < 4; ++j) {
            o[i][j].x = fmaf(pik, vv[j].x, o[i][j].x);
            o[i][j].y = fmaf(pik, vv[j].y, o[i][j].y);
            o[i][j].z = fmaf(pik, vv[j].z, o[i][j].z);
            o[i][j].w = fmaf(pik, vv[j].w, o[i][j].w);
          }
        }
      }
    }
  }

  // ---- epilogue: ctx[b][c][n] = 2 * o / l  (x2 = the ctx+ctx in the ref) ----
#pragma unroll
  for (int i = 0; i < 4; ++i) {
    float inv = 2.f / l[i];
    int n = q0 + tq * 4 + i;
#pragma unroll
    for (int j = 0; j < 4; ++j) {
      int cb = tk * 4 + j * 64;
      size_t base = ((size_t)b * CC + cb) * NN + n;
      ctx[base + 0 * NN] = o[i][j].x * inv;
      ctx[base + 1 * NN] = o[i][j].y * inv;
      ctx[base + 2 * NN] = o[i][j].z * inv;
      ctx[base + 3 * NN] = o[i][j].w * inv;
    }
  }
}

extern "C" void kernel_launch(void* const* d_in, const int* in_sizes, int n_in,
                              void* d_out, int out_size, void* d_ws, size_t ws_size,
                              hipStream_t stream) {
  const float* x  = (const float*)d_in[0];
  const float* wq = (const float*)d_in[1];
  const float* bq = (const float*)d_in[2];
  const float* wk = (const float*)d_in[3];
  const float* bk = (const float*)d_in[4];
  const float* wv = (const float*)d_in[5];
  const float* bv = (const float*)d_in[6];
  const float* wo = (const float*)d_in[7];
  const float* bo = (const float*)d_in[8];

  size_t n_el = (size_t)BB * CC * HH * WW;  // 4,194,304
  float* qT  = (float*)d_ws;
  float* kT  = qT + n_el;
  float* vT  = kT + n_el;
  float* ctx = vT + n_el;   // needs 4*16.78MB = 67.1 MB of ws

  dim3 cgrid(BB * HH * 64);  // 16384 blocks
  conv3_k<<<cgrid, 256, 0, stream>>>(x, wq, bq, qT, 1);
  conv3_k<<<cgrid, 256, 0, stream>>>(x, wk, bk, kT, 1);
  conv3_k<<<cgrid, 256, 0, stream>>>(x, wv, bv, vT, 1);
  attn_k<<<dim3(BB * 64), 256, 0, stream>>>(qT, kT, vT, ctx);
  conv3_k<<<cgrid, 256, 0, stream>>>(ctx, wo, bo, (float*)d_out, 0);
}

// Round 2
// 1774.102 us; speedup vs baseline: 6.2912x; 6.2912x over previous
//
#include <hip/hip_runtime.h>
#include <hip/hip_fp16.h>
#include <math.h>

#define NN 4096
#define CC 256

typedef __attribute__((ext_vector_type(8))) short bf16x8;
typedef __attribute__((ext_vector_type(4))) float f32x4;
typedef __attribute__((ext_vector_type(8))) unsigned short u16x8;
typedef __attribute__((ext_vector_type(4))) unsigned short u16x4;

__device__ inline unsigned short f2bf(float f) {
  unsigned u = __float_as_uint(f);
  return (unsigned short)((u + 0x7FFFu + ((u >> 16) & 1u)) >> 16);
}
__device__ inline float bf2f(unsigned short u) {
  return __uint_as_float(((unsigned)u) << 16);
}
__device__ inline float h2f(unsigned short u) {
  __half_raw r; r.x = u; return __half2float(__half(r));
}
__device__ inline unsigned short f2h(float f) {
  __half h = __float2half(f);
  return static_cast<__half_raw>(h).x;
}

// async global->LDS, 16B per lane; dest = wave-uniform base + lane*16
__device__ inline void gload16(const void* g, void* l) {
  __builtin_amdgcn_global_load_lds(
      (const __attribute__((address_space(1))) void*)g,
      (__attribute__((address_space(3))) void*)l, 16, 0, 0);
}

// ---------------------------------------------------------------------------
// prep_w: w [co][ci][3][3] f32 -> wT2 [9][co][ci] bf16 (B^T layout per shift).
// Also zeroes the 256B zero-page (used to mask out-of-bounds conv rows).
// ---------------------------------------------------------------------------
__global__ __launch_bounds__(256) void prep_w(
    const float* __restrict__ w0, const float* __restrict__ w1,
    const float* __restrict__ w2, const float* __restrict__ w3,
    unsigned short* __restrict__ wT2, unsigned short* __restrict__ zp)
{
  int bx = blockIdx.x;
  int widx = bx >> 8;
  const float* src = (widx == 0) ? w0 : (widx == 1) ? w1 : (widx == 2) ? w2 : w3;
  int p = ((bx & 255) << 8) + threadIdx.x;          // p = co*256 + ci
  unsigned short* dst = wT2 + (size_t)widx * 589824;
  const float* s9 = src + (size_t)p * 9;
#pragma unroll
  for (int s = 0; s < 9; ++s) dst[(size_t)s * 65536 + p] = f2bf(s9[s]);
  if (bx == 0 && threadIdx.x < 128) zp[threadIdx.x] = 0;
}

// ---------------------------------------------------------------------------
// prep_x: x [B][C][H][W] f32 -> xT [B][N][C] bf16 (LDS tile transpose).
// ---------------------------------------------------------------------------
__global__ __launch_bounds__(256) void prep_x(
    const float* __restrict__ x, unsigned short* __restrict__ xT)
{
  __shared__ unsigned short T[64][72];
  int tid = threadIdx.x, bx = blockIdx.x;
  int b = bx >> 8, c0 = ((bx >> 6) & 3) * 64, n0 = (bx & 63) * 64;
#pragma unroll
  for (int it = 0; it < 16; ++it) {
    int c_l = (tid >> 6) + it * 4;
    int n_l = tid & 63;
    T[n_l][c_l] = f2bf(x[((size_t)(b * 256 + c0 + c_l)) * 4096 + n0 + n_l]);
  }
  __syncthreads();
#pragma unroll
  for (int it = 0; it < 8; ++it) {
    int n_l = (tid >> 5) + it * 8;
    int cp = (tid & 31) * 2;
    unsigned v = (unsigned)T[n_l][cp] | ((unsigned)T[n_l][cp + 1] << 16);
    *(unsigned*)&xT[((size_t)(b * 4096 + n0 + n_l)) * 256 + c0 + cp] = v;
  }
}

// ---------------------------------------------------------------------------
// conv_mfma: 3x3 SAME conv as 9 accumulated GEMMs, bf16 MFMA 16x16x32.
// A: bf16 [16384][256] channels-last.  W: bf16 [9][co][ci].  bias fp32.
// mode 0: out = fp16 [B][N][C] (relu)    mode 1: out = f32 [B][C][H][W] (relu)
// Block: 128(M) x 128(N=co) tile, 4 waves, 64x64 per wave, BK=64,
// double-buffered LDS staged via global_load_lds with XOR-swizzled sources.
// ---------------------------------------------------------------------------
__global__ __launch_bounds__(256) void conv_mfma(
    const unsigned short* __restrict__ A,
    const unsigned short* __restrict__ W,
    const float* __restrict__ bias,
    void* __restrict__ out, int mode,
    const unsigned short* __restrict__ zp)
{
  __shared__ unsigned short As[2][128 * 64];
  __shared__ unsigned short Bs[2][128 * 64];

  const int tid = threadIdx.x;
  const int lane = tid & 63;
  const int w = tid >> 6;
  const int wr = w >> 1, wc = w & 1;
  const int nt = blockIdx.x & 1;
  const int mt = blockIdx.x >> 1;
  const int m0 = mt * 128;
  const int co0 = nt * 128;

  // staging geometry: lane covers (row = base+lane>>3, phys slot = lane&7)
  const int aslot = (lane & 7) ^ (lane >> 3);   // pre-swizzled source slot
  int gmj[4], yj[4], xj[4], browj[4];
#pragma unroll
  for (int j = 0; j < 4; ++j) {
    int row = w * 32 + j * 8 + (lane >> 3);
    int gm = m0 + row;
    gmj[j] = gm;
    int n = gm & (NN - 1);
    yj[j] = n >> 6;
    xj[j] = n & 63;
    browj[j] = co0 + row;
  }

  f32x4 acc[4][4];
#pragma unroll
  for (int mi = 0; mi < 4; ++mi)
#pragma unroll
    for (int ni = 0; ni < 4; ++ni) acc[mi][ni] = (f32x4){0.f, 0.f, 0.f, 0.f};

  auto stage = [&](int step, int sb) {
    int s = step >> 2, t = step & 3;
    int dy = s / 3 - 1, dx = s - (s / 3) * 3 - 1;
    const unsigned short* abase = A + t * 64 + aslot * 8;
    const unsigned short* wbase = W + ((size_t)s << 16) + t * 64 + aslot * 8;
#pragma unroll
    for (int j = 0; j < 4; ++j) {
      int yy = yj[j] + dy, xx = xj[j] + dx;
      bool valid = ((unsigned)yy < 64u) && ((unsigned)xx < 64u);
      const void* ga = valid
          ? (const void*)(abase + (size_t)(gmj[j] + dy * 64 + dx) * 256)
          : (const void*)zp;
      gload16(ga, (void*)&As[sb][(w * 4 + j) * 512]);
      const void* gb = (const void*)(wbase + (size_t)browj[j] * 256);
      gload16(gb, (void*)&Bs[sb][(w * 4 + j) * 512]);
    }
  };

  const int r = lane & 15;
  const int klane = lane >> 4;
  const int rs = r & 7;

  int buf = 0;
  stage(0, 0);
  __syncthreads();
  for (int step = 0; step < 36; ++step) {
    if (step + 1 < 36) stage(step + 1, buf ^ 1);
    const unsigned short* as = As[buf];
    const unsigned short* bs = Bs[buf];
#pragma unroll
    for (int kk = 0; kk < 2; ++kk) {
      int slot = (kk * 4 + klane) ^ rs;
      bf16x8 a[4], bq[4];
#pragma unroll
      for (int mi = 0; mi < 4; ++mi)
        a[mi] = *(const bf16x8*)&as[(wr * 64 + mi * 16 + r) * 64 + slot * 8];
#pragma unroll
      for (int ni = 0; ni < 4; ++ni)
        bq[ni] = *(const bf16x8*)&bs[(wc * 64 + ni * 16 + r) * 64 + slot * 8];
#pragma unroll
      for (int mi = 0; mi < 4; ++mi)
#pragma unroll
        for (int ni = 0; ni < 4; ++ni)
          acc[mi][ni] = __builtin_amdgcn_mfma_f32_16x16x32_bf16(
              a[mi], bq[ni], acc[mi][ni], 0, 0, 0);
    }
    __syncthreads();
    buf ^= 1;
  }

  // epilogue
  const int r4 = lane >> 4;
  const int colb = lane & 15;
  if (mode == 0) {
    unsigned short* o16 = (unsigned short*)out;
#pragma unroll
    for (int ni = 0; ni < 4; ++ni) {
      int co = co0 + wc * 64 + ni * 16 + colb;
      float bv = bias[co];
#pragma unroll
      for (int mi = 0; mi < 4; ++mi) {
        int gm0 = m0 + wr * 64 + mi * 16 + r4 * 4;
#pragma unroll
        for (int rr = 0; rr < 4; ++rr) {
          float v = fmaxf(acc[mi][ni][rr] + bv, 0.f);
          o16[(size_t)(gm0 + rr) * 256 + co] = f2h(v);
        }
      }
    }
  } else {
    float* o32 = (float*)out;
#pragma unroll
    for (int ni = 0; ni < 4; ++ni) {
      int co = co0 + wc * 64 + ni * 16 + colb;
      float bv = bias[co];
#pragma unroll
      for (int mi = 0; mi < 4; ++mi) {
        int gm0 = m0 + wr * 64 + mi * 16 + r4 * 4;
#pragma unroll
        for (int rr = 0; rr < 4; ++rr) {
          float v = fmaxf(acc[mi][ni][rr] + bv, 0.f);
          int gm = gm0 + rr;
          int b = gm >> 12, n = gm & (NN - 1);
          o32[((size_t)(b * 256 + co)) * 4096 + n] = v;
        }
      }
    }
  }
}

// ---------------------------------------------------------------------------
// Flash-style attention, fp32 compute, fp16 Q/K/V input [B][N][C],
// bf16 ctx output [B][N][C] (already scaled by 2 = ctx+ctx in the ref).
// ---------------------------------------------------------------------------
__global__ __launch_bounds__(256) void attn_k(
    const unsigned short* __restrict__ qT, const unsigned short* __restrict__ kT,
    const unsigned short* __restrict__ vT, unsigned short* __restrict__ ctx)
{
  __shared__ float Qs[64][260];
  __shared__ float Ks[32][260];
  __shared__ float Vs[32][260];
  __shared__ float Ps[64][36];

  int tid = threadIdx.x;
  int b   = blockIdx.x >> 6;
  int q0  = (blockIdx.x & 63) << 6;
  int tq  = tid >> 4;
  int tk  = tid & 15;

  const unsigned short* qTb = qT + ((size_t)(b * NN + q0)) * CC;

  // stage Q tile [64][256] (fp16 -> f32)
  for (int i = tid; i < 64 * 32; i += 256) {
    int rr = i >> 5, ch = i & 31;
    u16x8 hv = *(const u16x8*)(qTb + rr * 256 + ch * 8);
    float* dst = &Qs[rr][ch * 8];
#pragma unroll
    for (int e = 0; e < 8; ++e) dst[e] = h2f(hv[e]);
  }

  float m[4], l[4];
  float4 o[4][4];
#pragma unroll
  for (int i = 0; i < 4; ++i) {
    m[i] = -INFINITY;
    l[i] = 0.f;
#pragma unroll
    for (int j = 0; j < 4; ++j) o[i][j] = make_float4(0.f, 0.f, 0.f, 0.f);
  }

  for (int ch = 0; ch < NN / 32; ++ch) {
    __syncthreads();
    const unsigned short* kTb = kT + ((size_t)(b * NN + ch * 32)) * CC;
    const unsigned short* vTb = vT + ((size_t)(b * NN + ch * 32)) * CC;
    for (int i = tid; i < 32 * 32; i += 256) {
      int rr = i >> 5, cc = i & 31;
      u16x8 kv = *(const u16x8*)(kTb + rr * 256 + cc * 8);
      u16x8 vv = *(const u16x8*)(vTb + rr * 256 + cc * 8);
      float* dk = &Ks[rr][cc * 8];
      float* dv = &Vs[rr][cc * 8];
#pragma unroll
      for (int e = 0; e < 8; ++e) { dk[e] = h2f(kv[e]); dv[e] = h2f(vv[e]); }
    }
    __syncthreads();

    // ---- scores ----
    float s[4][2] = {{0.f,0.f},{0.f,0.f},{0.f,0.f},{0.f,0.f}};
    int k0 = tk * 2;
    for (int cb = 0; cb < 64; ++cb) {
      float4 kv0 = *(const float4*)&Ks[k0][cb * 4];
      float4 kv1 = *(const float4*)&Ks[k0 + 1][cb * 4];
#pragma unroll
      for (int i = 0; i < 4; ++i) {
        float4 qv = *(const float4*)&Qs[tq * 4 + i][cb * 4];
        s[i][0] += qv.x*kv0.x + qv.y*kv0.y + qv.z*kv0.z + qv.w*kv0.w;
        s[i][1] += qv.x*kv1.x + qv.y*kv1.y + qv.z*kv1.z + qv.w*kv1.w;
      }
    }

    // ---- online softmax ----
#pragma unroll
    for (int i = 0; i < 4; ++i) {
      float cmax = fmaxf(s[i][0], s[i][1]);
      for (int off = 1; off < 16; off <<= 1)
        cmax = fmaxf(cmax, __shfl_xor(cmax, off));
      float mnew = fmaxf(m[i], cmax);
      float sc   = __expf(m[i] - mnew);
      float p0   = __expf(s[i][0] - mnew);
      float p1   = __expf(s[i][1] - mnew);
      float ps   = p0 + p1;
      for (int off = 1; off < 16; off <<= 1)
        ps += __shfl_xor(ps, off);
      l[i] = l[i] * sc + ps;
      m[i] = mnew;
      Ps[tq * 4 + i][k0]     = p0;
      Ps[tq * 4 + i][k0 + 1] = p1;
#pragma unroll
      for (int j = 0; j < 4; ++j) {
        o[i][j].x *= sc; o[i][j].y *= sc; o[i][j].z *= sc; o[i][j].w *= sc;
      }
    }
    __syncthreads();

    // ---- PV ----
#pragma unroll
    for (int k4 = 0; k4 < 8; ++k4) {
      float4 p[4];
#pragma unroll
      for (int i = 0; i < 4; ++i)
        p[i] = *(const float4*)&Ps[tq * 4 + i][k4 * 4];
#pragma unroll
      for (int kk = 0; kk < 4; ++kk) {
        int k = k4 * 4 + kk;
        float4 vv[4];
#pragma unroll
        for (int j = 0; j < 4; ++j)
          vv[j] = *(const float4*)&Vs[k][tk * 4 + j * 64];
#pragma unroll
        for (int i = 0; i < 4; ++i) {
          float pik = (kk == 0) ? p[i].x : (kk == 1) ? p[i].y
                    : (kk == 2) ? p[i].z : p[i].w;
#pragma unroll
          for (int j = 0; j < 4; ++j) {
            o[i][j].x = fmaf(pik, vv[j].x, o[i][j].x);
            o[i][j].y = fmaf(pik, vv[j].y, o[i][j].y);
            o[i][j].z = fmaf(pik, vv[j].z, o[i][j].z);
            o[i][j].w = fmaf(pik, vv[j].w, o[i][j].w);
          }
        }
      }
    }
  }

  // ---- epilogue: ctx[b][n][c] bf16 = 2 * o / l ----
#pragma unroll
  for (int i = 0; i < 4; ++i) {
    float inv = 2.f / l[i];
    int n = q0 + tq * 4 + i;
#pragma unroll
    for (int j = 0; j < 4; ++j) {
      int cb = tk * 4 + j * 64;
      u16x4 pk;
      pk[0] = f2bf(o[i][j].x * inv);
      pk[1] = f2bf(o[i][j].y * inv);
      pk[2] = f2bf(o[i][j].z * inv);
      pk[3] = f2bf(o[i][j].w * inv);
      *(u16x4*)&ctx[((size_t)(b * NN + n)) * CC + cb] = pk;
    }
  }
}

extern "C" void kernel_launch(void* const* d_in, const int* in_sizes, int n_in,
                              void* d_out, int out_size, void* d_ws, size_t ws_size,
                              hipStream_t stream) {
  const float* x  = (const float*)d_in[0];
  const float* wq = (const float*)d_in[1];
  const float* bq = (const float*)d_in[2];
  const float* wk = (const float*)d_in[3];
  const float* bk = (const float*)d_in[4];
  const float* wv = (const float*)d_in[5];
  const float* bv = (const float*)d_in[6];
  const float* wo = (const float*)d_in[7];
  const float* bo = (const float*)d_in[8];

  char* ws = (char*)d_ws;
  unsigned short* xT  = (unsigned short*)(ws);              //  8,388,608 B bf16 [B][N][C]
  unsigned short* wT2 = (unsigned short*)(ws + 8388608);    //  4,718,592 B bf16 [4][9][co][ci]
  unsigned short* qT  = (unsigned short*)(ws + 13107200);   //  8,388,608 B fp16 [B][N][C]
  unsigned short* kT  = (unsigned short*)(ws + 21495808);   //  8,388,608 B
  unsigned short* vT  = (unsigned short*)(ws + 29884416);   //  8,388,608 B
  unsigned short* ctx = (unsigned short*)(ws + 38273024);   //  8,388,608 B bf16 [B][N][C]
  unsigned short* zp  = (unsigned short*)(ws + 46661632);   //  256 B zeros

  prep_w<<<dim3(1024), 256, 0, stream>>>(wq, wk, wv, wo, wT2, zp);
  prep_x<<<dim3(1024), 256, 0, stream>>>(x, xT);
  conv_mfma<<<dim3(256), 256, 0, stream>>>(xT, wT2,               bq, qT, 0, zp);
  conv_mfma<<<dim3(256), 256, 0, stream>>>(xT, wT2 + 589824,      bk, kT, 0, zp);
  conv_mfma<<<dim3(256), 256, 0, stream>>>(xT, wT2 + 2 * 589824,  bv, vT, 0, zp);
  attn_k<<<dim3(256), 256, 0, stream>>>(qT, kT, vT, ctx);
  conv_mfma<<<dim3(256), 256, 0, stream>>>(ctx, wT2 + 3 * 589824, bo, (float*)d_out, 1, zp);
}

// Round 3
// 412.705 us; speedup vs baseline: 27.0440x; 4.2987x over previous
//
#include <hip/hip_runtime.h>
#include <hip/hip_fp16.h>
#include <math.h>

#define NN 4096
#define CC 256

typedef __attribute__((ext_vector_type(8))) short bf16x8;
typedef __attribute__((ext_vector_type(8))) _Float16 f16x8;
typedef __attribute__((ext_vector_type(4))) float f32x4;
typedef __attribute__((ext_vector_type(8))) unsigned short u16x8;
typedef __attribute__((ext_vector_type(4))) unsigned short u16x4;

__device__ inline unsigned short f2bf(float f) {
  unsigned u = __float_as_uint(f);
  return (unsigned short)((u + 0x7FFFu + ((u >> 16) & 1u)) >> 16);
}
__device__ inline unsigned short f2h(float f) {
  __half h = __float2half(f);
  return static_cast<__half_raw>(h).x;
}

// async global->LDS, 16B per lane; dest = wave-uniform base + lane*16
__device__ inline void gload16(const void* g, void* l) {
  __builtin_amdgcn_global_load_lds(
      (const __attribute__((address_space(1))) void*)g,
      (__attribute__((address_space(3))) void*)l, 16, 0, 0);
}

// ---------------------------------------------------------------------------
// prep_w: w [co][ci][3][3] f32 -> wT2 [9][co][ci] bf16 (B^T layout per shift).
// Also zeroes the 256B zero-page.
// ---------------------------------------------------------------------------
__global__ __launch_bounds__(256) void prep_w(
    const float* __restrict__ w0, const float* __restrict__ w1,
    const float* __restrict__ w2, const float* __restrict__ w3,
    unsigned short* __restrict__ wT2, unsigned short* __restrict__ zp)
{
  int bx = blockIdx.x;
  int widx = bx >> 8;
  const float* src = (widx == 0) ? w0 : (widx == 1) ? w1 : (widx == 2) ? w2 : w3;
  int p = ((bx & 255) << 8) + threadIdx.x;          // p = co*256 + ci
  unsigned short* dst = wT2 + (size_t)widx * 589824;
  const float* s9 = src + (size_t)p * 9;
#pragma unroll
  for (int s = 0; s < 9; ++s) dst[(size_t)s * 65536 + p] = f2bf(s9[s]);
  if (bx == 0 && threadIdx.x < 128) zp[threadIdx.x] = 0;
}

// ---------------------------------------------------------------------------
// prep_x: x [B][C][H][W] f32 -> xT [B][N][C] bf16.
// ---------------------------------------------------------------------------
__global__ __launch_bounds__(256) void prep_x(
    const float* __restrict__ x, unsigned short* __restrict__ xT)
{
  __shared__ unsigned short T[64][72];
  int tid = threadIdx.x, bx = blockIdx.x;
  int b = bx >> 8, c0 = ((bx >> 6) & 3) * 64, n0 = (bx & 63) * 64;
#pragma unroll
  for (int it = 0; it < 16; ++it) {
    int c_l = (tid >> 6) + it * 4;
    int n_l = tid & 63;
    T[n_l][c_l] = f2bf(x[((size_t)(b * 256 + c0 + c_l)) * 4096 + n0 + n_l]);
  }
  __syncthreads();
#pragma unroll
  for (int it = 0; it < 8; ++it) {
    int n_l = (tid >> 5) + it * 8;
    int cp = (tid & 31) * 2;
    unsigned v = (unsigned)T[n_l][cp] | ((unsigned)T[n_l][cp + 1] << 16);
    *(unsigned*)&xT[((size_t)(b * 4096 + n0 + n_l)) * 256 + c0 + cp] = v;
  }
}

// ---------------------------------------------------------------------------
// conv_mfma: 3x3 SAME conv as 9 accumulated GEMMs, bf16 MFMA 16x16x32.
// mode 0: fp16 [B][N][C]   mode 1: f32 [B][C][H][W]   mode 2: fp16 [B][C][N]
// ---------------------------------------------------------------------------
__global__ __launch_bounds__(256) void conv_mfma(
    const unsigned short* __restrict__ A,
    const unsigned short* __restrict__ W,
    const float* __restrict__ bias,
    void* __restrict__ out, int mode,
    const unsigned short* __restrict__ zp)
{
  __shared__ unsigned short As[2][128 * 64];
  __shared__ unsigned short Bs[2][128 * 64];

  const int tid = threadIdx.x;
  const int lane = tid & 63;
  const int w = tid >> 6;
  const int wr = w >> 1, wc = w & 1;
  const int nt = blockIdx.x & 1;
  const int mt = blockIdx.x >> 1;
  const int m0 = mt * 128;
  const int co0 = nt * 128;

  const int aslot = (lane & 7) ^ (lane >> 3);
  int gmj[4], yj[4], xj[4], browj[4];
#pragma unroll
  for (int j = 0; j < 4; ++j) {
    int row = w * 32 + j * 8 + (lane >> 3);
    int gm = m0 + row;
    gmj[j] = gm;
    int n = gm & (NN - 1);
    yj[j] = n >> 6;
    xj[j] = n & 63;
    browj[j] = co0 + row;
  }

  f32x4 acc[4][4];
#pragma unroll
  for (int mi = 0; mi < 4; ++mi)
#pragma unroll
    for (int ni = 0; ni < 4; ++ni) acc[mi][ni] = (f32x4){0.f, 0.f, 0.f, 0.f};

  auto stage = [&](int step, int sb) {
    int s = step >> 2, t = step & 3;
    int dy = s / 3 - 1, dx = s - (s / 3) * 3 - 1;
    const unsigned short* abase = A + t * 64 + aslot * 8;
    const unsigned short* wbase = W + ((size_t)s << 16) + t * 64 + aslot * 8;
#pragma unroll
    for (int j = 0; j < 4; ++j) {
      int yy = yj[j] + dy, xx = xj[j] + dx;
      bool valid = ((unsigned)yy < 64u) && ((unsigned)xx < 64u);
      const void* ga = valid
          ? (const void*)(abase + (size_t)(gmj[j] + dy * 64 + dx) * 256)
          : (const void*)zp;
      gload16(ga, (void*)&As[sb][(w * 4 + j) * 512]);
      const void* gb = (const void*)(wbase + (size_t)browj[j] * 256);
      gload16(gb, (void*)&Bs[sb][(w * 4 + j) * 512]);
    }
  };

  const int r = lane & 15;
  const int klane = lane >> 4;
  const int rs = r & 7;

  int buf = 0;
  stage(0, 0);
  __syncthreads();
  for (int step = 0; step < 36; ++step) {
    if (step + 1 < 36) stage(step + 1, buf ^ 1);
    const unsigned short* as = As[buf];
    const unsigned short* bs = Bs[buf];
#pragma unroll
    for (int kk = 0; kk < 2; ++kk) {
      int slot = (kk * 4 + klane) ^ rs;
      bf16x8 a[4], bq[4];
#pragma unroll
      for (int mi = 0; mi < 4; ++mi)
        a[mi] = *(const bf16x8*)&as[(wr * 64 + mi * 16 + r) * 64 + slot * 8];
#pragma unroll
      for (int ni = 0; ni < 4; ++ni)
        bq[ni] = *(const bf16x8*)&bs[(wc * 64 + ni * 16 + r) * 64 + slot * 8];
#pragma unroll
      for (int mi = 0; mi < 4; ++mi)
#pragma unroll
        for (int ni = 0; ni < 4; ++ni)
          acc[mi][ni] = __builtin_amdgcn_mfma_f32_16x16x32_bf16(
              a[mi], bq[ni], acc[mi][ni], 0, 0, 0);
    }
    __syncthreads();
    buf ^= 1;
  }

  const int r4 = lane >> 4;
  const int colb = lane & 15;
  if (mode == 0) {
    unsigned short* o16 = (unsigned short*)out;
#pragma unroll
    for (int ni = 0; ni < 4; ++ni) {
      int co = co0 + wc * 64 + ni * 16 + colb;
      float bv = bias[co];
#pragma unroll
      for (int mi = 0; mi < 4; ++mi) {
        int gm0 = m0 + wr * 64 + mi * 16 + r4 * 4;
#pragma unroll
        for (int rr = 0; rr < 4; ++rr) {
          float v = fmaxf(acc[mi][ni][rr] + bv, 0.f);
          o16[(size_t)(gm0 + rr) * 256 + co] = f2h(v);
        }
      }
    }
  } else if (mode == 1) {
    float* o32 = (float*)out;
#pragma unroll
    for (int ni = 0; ni < 4; ++ni) {
      int co = co0 + wc * 64 + ni * 16 + colb;
      float bv = bias[co];
#pragma unroll
      for (int mi = 0; mi < 4; ++mi) {
        int gm0 = m0 + wr * 64 + mi * 16 + r4 * 4;
#pragma unroll
        for (int rr = 0; rr < 4; ++rr) {
          float v = fmaxf(acc[mi][ni][rr] + bv, 0.f);
          int gm = gm0 + rr;
          int b = gm >> 12, n = gm & (NN - 1);
          o32[((size_t)(b * 256 + co)) * 4096 + n] = v;
        }
      }
    }
  } else {
    unsigned short* o16 = (unsigned short*)out;
#pragma unroll
    for (int ni = 0; ni < 4; ++ni) {
      int co = co0 + wc * 64 + ni * 16 + colb;
      float bv = bias[co];
#pragma unroll
      for (int mi = 0; mi < 4; ++mi) {
        int gm0 = m0 + wr * 64 + mi * 16 + r4 * 4;
#pragma unroll
        for (int rr = 0; rr < 4; ++rr) {
          float v = fmaxf(acc[mi][ni][rr] + bv, 0.f);
          int gm = gm0 + rr;
          int b = gm >> 12, n = gm & (NN - 1);
          o16[((size_t)(b * 256 + co)) * 4096 + n] = f2h(v);
        }
      }
    }
  }
}

// ---------------------------------------------------------------------------
// MFMA flash attention, fp16 in / f32 accum.
// qT,kT: fp16 [B][N][C].  vTc: fp16 [B][C][N].  ctx out: bf16 [B][N][C], x2.
// Block = 256 thr = 4 waves, 64 queries (wave w owns q rows 16w..16w+15, Q in
// registers).  K chunk [64][256] and Vt chunk [256][64] double-buffered in
// LDS, XOR-swizzled (16B slot ^ (row&7)) via pre-swizzled global_load_lds
// sources.  P via 8KB swizzled LDS tile.  One barrier per chunk.
// ---------------------------------------------------------------------------
__global__ __launch_bounds__(256) void attn_k(
    const unsigned short* __restrict__ qT, const unsigned short* __restrict__ kT,
    const unsigned short* __restrict__ vTc, unsigned short* __restrict__ ctx)
{
  __shared__ unsigned short Ks[2][64 * 256];   // 2 x 32KB
  __shared__ unsigned short Vts[2][256 * 64];  // 2 x 32KB
  __shared__ unsigned short Ps[64 * 64];       // 8KB

  const int tid = threadIdx.x;
  const int lane = tid & 63;
  const int w = tid >> 6;
  const int l15 = lane & 15;
  const int kg = lane >> 4;           // 0..3
  const int b = blockIdx.x >> 6;
  const int q0 = (blockIdx.x & 63) << 6;

  // ---- Q into registers: rows q0+16w+l15, frag ks: c = ks*32 + kg*8 + j ----
  f16x8 qf[8];
  {
    const unsigned short* qp =
        qT + ((size_t)(b * NN) + q0 + 16 * w + l15) * CC + kg * 8;
#pragma unroll
    for (int ks = 0; ks < 8; ++ks)
      qf[ks] = *(const f16x8*)(qp + ks * 32);
  }

  // staging lambdas: wave-linear LDS dest, inverse-swizzled global source
  const unsigned short* kTb = kT + (size_t)b * NN * CC;
  const unsigned short* vTb = vTc + (size_t)b * CC * NN;
  auto stageKV = [&](int t, int sb) {
    int k0 = t << 6;
    // K: wave w stages rows 16w..16w+15; 8 issues of 1KB (2 rows each)
    {
      int row_l = (lane >> 5);            // 0..1
      int slot = lane & 31;               // 16B slot within 512B row
#pragma unroll
      for (int i = 0; i < 8; ++i) {
        int row = 16 * w + i * 2 + row_l;
        const void* src = (const void*)(kTb + (size_t)(k0 + row) * CC +
                                        ((slot ^ (row & 7)) << 3));
        gload16(src, (void*)&Ks[sb][(16 * w + i * 2) * 256]);
      }
    }
    // Vt: wave w stages channels 64w..64w+63; 8 issues of 1KB (8 rows each)
    {
      int c_l = (lane >> 3);              // 0..7
      int slot = lane & 7;                // 16B slot within 128B row
#pragma unroll
      for (int i = 0; i < 8; ++i) {
        int c = 64 * w + i * 8 + c_l;
        const void* src = (const void*)(vTb + (size_t)c * NN + k0 +
                                        ((slot ^ (c & 7)) << 3));
        gload16(src, (void*)&Vts[sb][(64 * w + i * 8) * 64]);
      }
    }
  };

  float m[4], l[4];
  f32x4 O[16];
#pragma unroll
  for (int i = 0; i < 4; ++i) { m[i] = -INFINITY; l[i] = 0.f; }
#pragma unroll
  for (int i = 0; i < 16; ++i) O[i] = (f32x4){0.f, 0.f, 0.f, 0.f};

  stageKV(0, 0);
  __syncthreads();

  int buf = 0;
  for (int t = 0; t < NN / 64; ++t) {
    if (t + 1 < NN / 64) stageKV(t + 1, buf ^ 1);

    // ---- QK^T: S[ni] = 16x16 frags, cols ni*16+l15, rows kg*4+reg ----
    f32x4 S[4];
#pragma unroll
    for (int ni = 0; ni < 4; ++ni) S[ni] = (f32x4){0.f, 0.f, 0.f, 0.f};
    const unsigned short* ks_ = Ks[buf];
#pragma unroll
    for (int ks = 0; ks < 8; ++ks) {
#pragma unroll
      for (int ni = 0; ni < 4; ++ni) {
        int krow = ni * 16 + l15;
        f16x8 bf = *(const f16x8*)&ks_[krow * 256 +
                                       ((((ks << 2) + kg) ^ (krow & 7)) << 3)];
        S[ni] = __builtin_amdgcn_mfma_f32_16x16x32_f16(qf[ks], bf, S[ni], 0, 0, 0);
      }
    }

    // ---- online softmax (rows kg*4+reg, 16-lane groups share rows) ----
#pragma unroll
    for (int reg = 0; reg < 4; ++reg) {
      float rmax = fmaxf(fmaxf(S[0][reg], S[1][reg]), fmaxf(S[2][reg], S[3][reg]));
#pragma unroll
      for (int off = 1; off < 16; off <<= 1)
        rmax = fmaxf(rmax, __shfl_xor(rmax, off));
      float mnew = fmaxf(m[reg], rmax);
      float sc = __expf(m[reg] - mnew);
      float p0 = __expf(S[0][reg] - mnew);
      float p1 = __expf(S[1][reg] - mnew);
      float p2 = __expf(S[2][reg] - mnew);
      float p3 = __expf(S[3][reg] - mnew);
      float rsum = (p0 + p1) + (p2 + p3);
#pragma unroll
      for (int off = 1; off < 16; off <<= 1)
        rsum += __shfl_xor(rsum, off);
      l[reg] = l[reg] * sc + rsum;
      m[reg] = mnew;
      int prow = 16 * w + kg * 4 + reg;
      int rx = prow & 7;
      int sl = l15 >> 3, so = l15 & 7;
      Ps[prow * 64 + (((0 + sl) ^ rx) << 3) + so] = f2h(p0);
      Ps[prow * 64 + (((2 + sl) ^ rx) << 3) + so] = f2h(p1);
      Ps[prow * 64 + (((4 + sl) ^ rx) << 3) + so] = f2h(p2);
      Ps[prow * 64 + (((6 + sl) ^ rx) << 3) + so] = f2h(p3);
#pragma unroll
      for (int oni = 0; oni < 16; ++oni) O[oni][reg] *= sc;
    }

    // ---- PV: O[ni] += P(16x64) * Vt(64 x 16cols) ----
    const unsigned short* vs_ = Vts[buf];
#pragma unroll
    for (int kk = 0; kk < 2; ++kk) {
      int prow = 16 * w + l15;
      f16x8 pa = *(const f16x8*)&Ps[prow * 64 +
                                    ((((kk << 2) + kg) ^ (prow & 7)) << 3)];
#pragma unroll
      for (int ni = 0; ni < 16; ++ni) {
        int c = ni * 16 + l15;
        f16x8 vb = *(const f16x8*)&vs_[c * 64 +
                                       ((((kk << 2) + kg) ^ (c & 7)) << 3)];
        O[ni] = __builtin_amdgcn_mfma_f32_16x16x32_f16(pa, vb, O[ni], 0, 0, 0);
      }
    }

    __syncthreads();
    buf ^= 1;
  }

  // ---- epilogue: ctx[b][n][c] bf16 = 2 * O / l ----
#pragma unroll
  for (int reg = 0; reg < 4; ++reg) {
    float inv = 2.f / l[reg];
    int n = q0 + 16 * w + kg * 4 + reg;
    unsigned short* dst = ctx + ((size_t)(b * NN) + n) * CC;
#pragma unroll
    for (int oni = 0; oni < 16; ++oni)
      dst[oni * 16 + l15] = f2bf(O[oni][reg] * inv);
  }
}

extern "C" void kernel_launch(void* const* d_in, const int* in_sizes, int n_in,
                              void* d_out, int out_size, void* d_ws, size_t ws_size,
                              hipStream_t stream) {
  const float* x  = (const float*)d_in[0];
  const float* wq = (const float*)d_in[1];
  const float* bq = (const float*)d_in[2];
  const float* wk = (const float*)d_in[3];
  const float* bk = (const float*)d_in[4];
  const float* wv = (const float*)d_in[5];
  const float* bv = (const float*)d_in[6];
  const float* wo = (const float*)d_in[7];
  const float* bo = (const float*)d_in[8];

  char* ws = (char*)d_ws;
  unsigned short* xT  = (unsigned short*)(ws);              // bf16 [B][N][C]
  unsigned short* wT2 = (unsigned short*)(ws + 8388608);    // bf16 [4][9][co][ci]
  unsigned short* qT  = (unsigned short*)(ws + 13107200);   // fp16 [B][N][C]
  unsigned short* kT  = (unsigned short*)(ws + 21495808);   // fp16 [B][N][C]
  unsigned short* vTc = (unsigned short*)(ws + 29884416);   // fp16 [B][C][N]
  unsigned short* ctx = (unsigned short*)(ws + 38273024);   // bf16 [B][N][C]
  unsigned short* zp  = (unsigned short*)(ws + 46661632);   // 256 B zeros

  prep_w<<<dim3(1024), 256, 0, stream>>>(wq, wk, wv, wo, wT2, zp);
  prep_x<<<dim3(1024), 256, 0, stream>>>(x, xT);
  conv_mfma<<<dim3(256), 256, 0, stream>>>(xT, wT2,               bq, qT, 0, zp);
  conv_mfma<<<dim3(256), 256, 0, stream>>>(xT, wT2 + 589824,      bk, kT, 0, zp);
  conv_mfma<<<dim3(256), 256, 0, stream>>>(xT, wT2 + 2 * 589824,  bv, vTc, 2, zp);
  attn_k<<<dim3(256), 256, 0, stream>>>(qT, kT, vTc, ctx);
  conv_mfma<<<dim3(256), 256, 0, stream>>>(ctx, wT2 + 3 * 589824, bo, (float*)d_out, 1, zp);
}

// Round 4
// 339.834 us; speedup vs baseline: 32.8431x; 1.2144x over previous
//
#include <hip/hip_runtime.h>
#include <hip/hip_fp16.h>
#include <math.h>

#define NN 4096
#define CC 256

typedef __attribute__((ext_vector_type(8))) short bf16x8;
typedef __attribute__((ext_vector_type(8))) _Float16 f16x8;
typedef __attribute__((ext_vector_type(2))) _Float16 f16x2;
typedef __attribute__((ext_vector_type(4))) float f32x4;
typedef __attribute__((ext_vector_type(16))) float f32x16;
typedef __attribute__((ext_vector_type(8))) unsigned short u16x8;
typedef __attribute__((ext_vector_type(4))) unsigned short u16x4;
typedef __attribute__((ext_vector_type(4))) unsigned int u32x4;

__device__ inline unsigned short f2bf(float f) {
  unsigned u = __float_as_uint(f);
  return (unsigned short)((u + 0x7FFFu + ((u >> 16) & 1u)) >> 16);
}
__device__ inline unsigned short f2h(float f) {
  __half h = __float2half(f);
  return static_cast<__half_raw>(h).x;
}

// async global->LDS, 16B per lane; dest = wave-uniform base + lane*16
__device__ inline void gload16(const void* g, void* l) {
  __builtin_amdgcn_global_load_lds(
      (const __attribute__((address_space(1))) void*)g,
      (__attribute__((address_space(3))) void*)l, 16, 0, 0);
}

// ---------------------------------------------------------------------------
// prep_w: w [co][ci][3][3] f32 -> wT2 [9][co][ci] bf16 (B^T layout per shift).
// ---------------------------------------------------------------------------
__global__ __launch_bounds__(256) void prep_w(
    const float* __restrict__ w0, const float* __restrict__ w1,
    const float* __restrict__ w2, const float* __restrict__ w3,
    unsigned short* __restrict__ wT2, unsigned short* __restrict__ zp)
{
  int bx = blockIdx.x;
  int widx = bx >> 8;
  const float* src = (widx == 0) ? w0 : (widx == 1) ? w1 : (widx == 2) ? w2 : w3;
  int p = ((bx & 255) << 8) + threadIdx.x;          // p = co*256 + ci
  unsigned short* dst = wT2 + (size_t)widx * 589824;
  const float* s9 = src + (size_t)p * 9;
#pragma unroll
  for (int s = 0; s < 9; ++s) dst[(size_t)s * 65536 + p] = f2bf(s9[s]);
  if (bx == 0 && threadIdx.x < 128) zp[threadIdx.x] = 0;
}

// ---------------------------------------------------------------------------
// prep_x: x [B][C][H][W] f32 -> xT [B][N][C] bf16.
// ---------------------------------------------------------------------------
__global__ __launch_bounds__(256) void prep_x(
    const float* __restrict__ x, unsigned short* __restrict__ xT)
{
  __shared__ unsigned short T[64][72];
  int tid = threadIdx.x, bx = blockIdx.x;
  int b = bx >> 8, c0 = ((bx >> 6) & 3) * 64, n0 = (bx & 63) * 64;
#pragma unroll
  for (int it = 0; it < 16; ++it) {
    int c_l = (tid >> 6) + it * 4;
    int n_l = tid & 63;
    T[n_l][c_l] = f2bf(x[((size_t)(b * 256 + c0 + c_l)) * 4096 + n0 + n_l]);
  }
  __syncthreads();
#pragma unroll
  for (int it = 0; it < 8; ++it) {
    int n_l = (tid >> 5) + it * 8;
    int cp = (tid & 31) * 2;
    unsigned v = (unsigned)T[n_l][cp] | ((unsigned)T[n_l][cp + 1] << 16);
    *(unsigned*)&xT[((size_t)(b * 4096 + n0 + n_l)) * 256 + c0 + cp] = v;
  }
}

// ---------------------------------------------------------------------------
// conv_mfma: 3x3 SAME conv as 9 accumulated GEMMs, bf16 MFMA 16x16x32.
// Tile 128(M) x 64(N) -> grid 512 blocks -> 2-3 blocks/CU for latency hiding.
// mode 0: fp16 [B][N][C]   mode 1: f32 [B][C][H][W]   mode 2: fp16 [B][C][N]
// ---------------------------------------------------------------------------
__global__ __launch_bounds__(256) void conv_mfma(
    const unsigned short* __restrict__ A,
    const unsigned short* __restrict__ W,
    const float* __restrict__ bias,
    void* __restrict__ out, int mode,
    const unsigned short* __restrict__ zp)
{
  __shared__ unsigned short As[2][128 * 64];   // 2 x 16KB
  __shared__ unsigned short Bs[2][64 * 64];    // 2 x 8KB

  const int tid = threadIdx.x;
  const int lane = tid & 63;
  const int w = tid >> 6;
  const int wr = w >> 1, wc = w & 1;
  const int nt = blockIdx.x & 3;
  const int mt = blockIdx.x >> 2;
  const int m0 = mt * 128;
  const int co0 = nt * 64;

  const int aslot = (lane & 7) ^ (lane >> 3);
  int gmj[4], yj[4], xj[4];
#pragma unroll
  for (int j = 0; j < 4; ++j) {
    int row = w * 32 + j * 8 + (lane >> 3);
    int gm = m0 + row;
    gmj[j] = gm;
    int n = gm & (NN - 1);
    yj[j] = n >> 6;
    xj[j] = n & 63;
  }
  int browj[2];
#pragma unroll
  for (int j = 0; j < 2; ++j)
    browj[j] = co0 + w * 16 + j * 8 + (lane >> 3);

  f32x4 acc[4][2];
#pragma unroll
  for (int mi = 0; mi < 4; ++mi)
#pragma unroll
    for (int ni = 0; ni < 2; ++ni) acc[mi][ni] = (f32x4){0.f, 0.f, 0.f, 0.f};

  auto stage = [&](int step, int sb) {
    int s = step >> 2, t = step & 3;
    int dy = s / 3 - 1, dx = s - (s / 3) * 3 - 1;
    const unsigned short* abase = A + t * 64 + aslot * 8;
    const unsigned short* wbase = W + ((size_t)s << 16) + t * 64 + aslot * 8;
#pragma unroll
    for (int j = 0; j < 4; ++j) {
      int yy = yj[j] + dy, xx = xj[j] + dx;
      bool valid = ((unsigned)yy < 64u) && ((unsigned)xx < 64u);
      const void* ga = valid
          ? (const void*)(abase + (size_t)(gmj[j] + dy * 64 + dx) * 256)
          : (const void*)zp;
      gload16(ga, (void*)&As[sb][(w * 4 + j) * 512]);
    }
#pragma unroll
    for (int j = 0; j < 2; ++j) {
      const void* gb = (const void*)(wbase + (size_t)browj[j] * 256);
      gload16(gb, (void*)&Bs[sb][(w * 2 + j) * 512]);
    }
  };

  const int r = lane & 15;
  const int klane = lane >> 4;
  const int rs = r & 7;

  int buf = 0;
  stage(0, 0);
  __syncthreads();
  for (int step = 0; step < 36; ++step) {
    if (step + 1 < 36) stage(step + 1, buf ^ 1);
    const unsigned short* as = As[buf];
    const unsigned short* bs = Bs[buf];
#pragma unroll
    for (int kk = 0; kk < 2; ++kk) {
      int slot = (kk * 4 + klane) ^ rs;
      bf16x8 a[4], bq[2];
#pragma unroll
      for (int mi = 0; mi < 4; ++mi)
        a[mi] = *(const bf16x8*)&as[(wr * 64 + mi * 16 + r) * 64 + slot * 8];
#pragma unroll
      for (int ni = 0; ni < 2; ++ni)
        bq[ni] = *(const bf16x8*)&bs[(wc * 32 + ni * 16 + r) * 64 + slot * 8];
#pragma unroll
      for (int mi = 0; mi < 4; ++mi)
#pragma unroll
        for (int ni = 0; ni < 2; ++ni)
          acc[mi][ni] = __builtin_amdgcn_mfma_f32_16x16x32_bf16(
              a[mi], bq[ni], acc[mi][ni], 0, 0, 0);
    }
    __syncthreads();
    buf ^= 1;
  }

  const int r4 = lane >> 4;
  const int colb = lane & 15;
  if (mode == 0) {
    unsigned short* o16 = (unsigned short*)out;
#pragma unroll
    for (int ni = 0; ni < 2; ++ni) {
      int co = co0 + wc * 32 + ni * 16 + colb;
      float bv = bias[co];
#pragma unroll
      for (int mi = 0; mi < 4; ++mi) {
        int gm0 = m0 + wr * 64 + mi * 16 + r4 * 4;
#pragma unroll
        for (int rr = 0; rr < 4; ++rr) {
          float v = fmaxf(acc[mi][ni][rr] + bv, 0.f);
          o16[(size_t)(gm0 + rr) * 256 + co] = f2h(v);
        }
      }
    }
  } else if (mode == 1) {
    float* o32 = (float*)out;
#pragma unroll
    for (int ni = 0; ni < 2; ++ni) {
      int co = co0 + wc * 32 + ni * 16 + colb;
      float bv = bias[co];
#pragma unroll
      for (int mi = 0; mi < 4; ++mi) {
        int gm0 = m0 + wr * 64 + mi * 16 + r4 * 4;
#pragma unroll
        for (int rr = 0; rr < 4; ++rr) {
          float v = fmaxf(acc[mi][ni][rr] + bv, 0.f);
          int gm = gm0 + rr;
          int b = gm >> 12, n = gm & (NN - 1);
          o32[((size_t)(b * 256 + co)) * 4096 + n] = v;
        }
      }
    }
  } else {
    unsigned short* o16 = (unsigned short*)out;
#pragma unroll
    for (int ni = 0; ni < 2; ++ni) {
      int co = co0 + wc * 32 + ni * 16 + colb;
      float bv = bias[co];
#pragma unroll
      for (int mi = 0; mi < 4; ++mi) {
        int gm0 = m0 + wr * 64 + mi * 16 + r4 * 4;
#pragma unroll
        for (int rr = 0; rr < 4; ++rr) {
          float v = fmaxf(acc[mi][ni][rr] + bv, 0.f);
          int gm = gm0 + rr;
          int b = gm >> 12, n = gm & (NN - 1);
          o16[((size_t)(b * 256 + co)) * 4096 + n] = f2h(v);
        }
      }
    }
  }
}

// ---------------------------------------------------------------------------
// MFMA flash attention v2: swapped-operand 32x32x16, in-register softmax.
// qT,kT: fp16 [B][N][C].  vTc: fp16 [B][C][N].  ctx out: bf16 [B][N][C], x2.
// 4 waves = (wq,wc).  Wave computes S^T[64 keys][32 q] = mfma(K, Q) -- lane
// holds 32 scores of ONE query (q = lane&31); max/sum = in-lane reduce + one
// permlane32_swap.  P packed to fp16 in-register (cvt_pkrtz + paired
// permlane32_swap), PV computes O^T = mfma(Vt, P) so O^T cols = q too.
// ---------------------------------------------------------------------------
__global__ __launch_bounds__(256, 1) void attn_k(
    const unsigned short* __restrict__ qT, const unsigned short* __restrict__ kT,
    const unsigned short* __restrict__ vTc, unsigned short* __restrict__ ctx)
{
  __shared__ unsigned short Ks[2][64 * 256];   // 2 x 32KB, [key][c], swizzled
  __shared__ unsigned short Vts[2][256 * 64];  // 2 x 32KB, [c][key], swizzled

  const int tid = threadIdx.x;
  const int lane = tid & 63;
  const int w = tid >> 6;
  const int wq = w >> 1, wc = w & 1;
  const int hi = lane >> 5;
  const int la = lane & 31;
  const int a7 = la & 7;
  const int b = blockIdx.x >> 6;
  const int q0 = (blockIdx.x & 63) << 6;

  // ---- Q as B-fragments: qf[ks] = Q[q0+32wq+la][16ks+8hi .. +8] ----
  f16x8 qf[16];
  {
    const unsigned short* qp =
        qT + ((size_t)(b * NN) + q0 + 32 * wq + la) * CC + 8 * hi;
#pragma unroll
    for (int ks = 0; ks < 16; ++ks)
      qf[ks] = *(const f16x8*)(qp + ks * 16);
  }

  // ---- staging: wave-linear LDS dest, inverse-swizzled global source ----
  const unsigned short* kTb = kT + (size_t)b * NN * CC;
  const unsigned short* vTb = vTc + (size_t)b * CC * NN;
  auto stageKV = [&](int t, int sb) {
    int k0 = t << 6;
    {
      int row_l = (lane >> 5);
      int slot = lane & 31;
#pragma unroll
      for (int i = 0; i < 8; ++i) {
        int row = 16 * w + i * 2 + row_l;
        const void* src = (const void*)(kTb + (size_t)(k0 + row) * CC +
                                        ((slot ^ (row & 7)) << 3));
        gload16(src, (void*)&Ks[sb][(16 * w + i * 2) * 256]);
      }
    }
    {
      int c_l = (lane >> 3);
      int slot = lane & 7;
#pragma unroll
      for (int i = 0; i < 8; ++i) {
        int c = 64 * w + i * 8 + c_l;
        const void* src = (const void*)(vTb + (size_t)c * NN + k0 +
                                        ((slot ^ (c & 7)) << 3));
        gload16(src, (void*)&Vts[sb][(64 * w + i * 8) * 64]);
      }
    }
  };

  float mprev = -INFINITY, lsum = 0.f;
  f32x16 O[4];
#pragma unroll
  for (int nc = 0; nc < 4; ++nc)
#pragma unroll
    for (int rr = 0; rr < 16; ++rr) O[nc][rr] = 0.f;

  stageKV(0, 0);
  __syncthreads();

  int buf = 0;
  for (int t = 0; t < NN / 64; ++t) {
    if (t + 1 < NN / 64) stageKV(t + 1, buf ^ 1);

    // ---- QK^T (swapped): S^T[key][q], two 32-key tiles ----
    f32x16 S0, S1;
#pragma unroll
    for (int rr = 0; rr < 16; ++rr) { S0[rr] = 0.f; S1[rr] = 0.f; }
    const unsigned short* ks_ = Ks[buf];
#pragma unroll
    for (int ks = 0; ks < 16; ++ks) {
      int sl = (((ks << 1) + hi) ^ a7) << 3;
      f16x8 a0 = *(const f16x8*)&ks_[la * 256 + sl];
      f16x8 a1 = *(const f16x8*)&ks_[(32 + la) * 256 + sl];
      S0 = __builtin_amdgcn_mfma_f32_32x32x16_f16(a0, qf[ks], S0, 0, 0, 0);
      S1 = __builtin_amdgcn_mfma_f32_32x32x16_f16(a1, qf[ks], S1, 0, 0, 0);
    }

    // ---- in-register online softmax (all 64 keys of q live in this lane
    //      pair: 32 here + 32 in lane^32) ----
    float mloc = S0[0];
#pragma unroll
    for (int rr = 1; rr < 16; ++rr) mloc = fmaxf(mloc, S0[rr]);
#pragma unroll
    for (int rr = 0; rr < 16; ++rr) mloc = fmaxf(mloc, S1[rr]);
    {
      auto sw = __builtin_amdgcn_permlane32_swap(
          __float_as_uint(mloc), __float_as_uint(mloc), false, false);
      mloc = fmaxf(__uint_as_float(sw[0]), __uint_as_float(sw[1]));
    }
    float mnew = fmaxf(mprev, mloc);
    float sc = __expf(mprev - mnew);
    float rs = 0.f;
#pragma unroll
    for (int rr = 0; rr < 16; ++rr) { S0[rr] = __expf(S0[rr] - mnew); rs += S0[rr]; }
#pragma unroll
    for (int rr = 0; rr < 16; ++rr) { S1[rr] = __expf(S1[rr] - mnew); rs += S1[rr]; }
    {
      auto sw = __builtin_amdgcn_permlane32_swap(
          __float_as_uint(rs), __float_as_uint(rs), false, false);
      rs = __uint_as_float(sw[0]) + __uint_as_float(sw[1]);
    }
    lsum = lsum * sc + rs;
    mprev = mnew;
#pragma unroll
    for (int nc = 0; nc < 4; ++nc)
#pragma unroll
      for (int rr = 0; rr < 16; ++rr) O[nc][rr] *= sc;

    // ---- pack P to fp16 A-row-fragments via paired permlane32_swap ----
    f16x8 pf[4];
#pragma unroll
    for (int kk = 0; kk < 4; ++kk) {
      const f32x16 Sm = (kk < 2) ? S0 : S1;
      const int r0 = (kk & 1) * 8;
      unsigned w0 = __builtin_bit_cast(unsigned,
          __builtin_amdgcn_cvt_pkrtz(Sm[r0 + 0], Sm[r0 + 1]));
      unsigned w1 = __builtin_bit_cast(unsigned,
          __builtin_amdgcn_cvt_pkrtz(Sm[r0 + 2], Sm[r0 + 3]));
      unsigned w2 = __builtin_bit_cast(unsigned,
          __builtin_amdgcn_cvt_pkrtz(Sm[r0 + 4], Sm[r0 + 5]));
      unsigned w3 = __builtin_bit_cast(unsigned,
          __builtin_amdgcn_cvt_pkrtz(Sm[r0 + 6], Sm[r0 + 7]));
      auto sA = __builtin_amdgcn_permlane32_swap(w0, w2, false, false);
      auto sB = __builtin_amdgcn_permlane32_swap(w1, w3, false, false);
      u32x4 fw;
      fw[0] = sA[0]; fw[1] = sB[0]; fw[2] = sA[1]; fw[3] = sB[1];
      pf[kk] = __builtin_bit_cast(f16x8, fw);
    }

    // ---- PV: O^T[c][q] += Vt-frag x P-frag ----
    const unsigned short* vs_ = Vts[buf];
#pragma unroll
    for (int kk = 0; kk < 4; ++kk) {
#pragma unroll
      for (int nc = 0; nc < 4; ++nc) {
        int c = 128 * wc + 32 * nc + la;
        f16x8 vf = *(const f16x8*)&vs_[c * 64 + ((((kk << 1) + hi) ^ a7) << 3)];
        O[nc] = __builtin_amdgcn_mfma_f32_32x32x16_f16(vf, pf[kk], O[nc], 0, 0, 0);
      }
    }

    __syncthreads();
    buf ^= 1;
  }

  // ---- epilogue: ctx[b][n][c] bf16 = 2 * O^T / l ----
  {
    float inv = 2.f / lsum;
    int n = q0 + 32 * wq + la;
    unsigned short* dst = ctx + ((size_t)(b * NN) + n) * CC;
#pragma unroll
    for (int nc = 0; nc < 4; ++nc) {
#pragma unroll
      for (int tq = 0; tq < 4; ++tq) {
        int c0 = 128 * wc + 32 * nc + 8 * tq + 4 * hi;
        u16x4 pk;
        pk[0] = f2bf(O[nc][4 * tq + 0] * inv);
        pk[1] = f2bf(O[nc][4 * tq + 1] * inv);
        pk[2] = f2bf(O[nc][4 * tq + 2] * inv);
        pk[3] = f2bf(O[nc][4 * tq + 3] * inv);
        *(u16x4*)&dst[c0] = pk;
      }
    }
  }
}

extern "C" void kernel_launch(void* const* d_in, const int* in_sizes, int n_in,
                              void* d_out, int out_size, void* d_ws, size_t ws_size,
                              hipStream_t stream) {
  const float* x  = (const float*)d_in[0];
  const float* wq = (const float*)d_in[1];
  const float* bq = (const float*)d_in[2];
  const float* wk = (const float*)d_in[3];
  const float* bk = (const float*)d_in[4];
  const float* wv = (const float*)d_in[5];
  const float* bv = (const float*)d_in[6];
  const float* wo = (const float*)d_in[7];
  const float* bo = (const float*)d_in[8];

  char* ws = (char*)d_ws;
  unsigned short* xT  = (unsigned short*)(ws);              // bf16 [B][N][C]
  unsigned short* wT2 = (unsigned short*)(ws + 8388608);    // bf16 [4][9][co][ci]
  unsigned short* qT  = (unsigned short*)(ws + 13107200);   // fp16 [B][N][C]
  unsigned short* kT  = (unsigned short*)(ws + 21495808);   // fp16 [B][N][C]
  unsigned short* vTc = (unsigned short*)(ws + 29884416);   // fp16 [B][C][N]
  unsigned short* ctx = (unsigned short*)(ws + 38273024);   // bf16 [B][N][C]
  unsigned short* zp  = (unsigned short*)(ws + 46661632);   // 256 B zeros

  prep_w<<<dim3(1024), 256, 0, stream>>>(wq, wk, wv, wo, wT2, zp);
  prep_x<<<dim3(1024), 256, 0, stream>>>(x, xT);
  conv_mfma<<<dim3(512), 256, 0, stream>>>(xT, wT2,               bq, qT, 0, zp);
  conv_mfma<<<dim3(512), 256, 0, stream>>>(xT, wT2 + 589824,      bk, kT, 0, zp);
  conv_mfma<<<dim3(512), 256, 0, stream>>>(xT, wT2 + 2 * 589824,  bv, vTc, 2, zp);
  attn_k<<<dim3(256), 256, 0, stream>>>(qT, kT, vTc, ctx);
  conv_mfma<<<dim3(512), 256, 0, stream>>>(ctx, wT2 + 3 * 589824, bo, (float*)d_out, 1, zp);
}

// Round 5
// 298.122 us; speedup vs baseline: 37.4384x; 1.1399x over previous
//
#include <hip/hip_runtime.h>
#include <hip/hip_fp16.h>
#include <math.h>

#define NN 4096
#define CC 256

typedef __attribute__((ext_vector_type(8))) short bf16x8;
typedef __attribute__((ext_vector_type(8))) _Float16 f16x8;
typedef __attribute__((ext_vector_type(4))) float f32x4;
typedef __attribute__((ext_vector_type(16))) float f32x16;
typedef __attribute__((ext_vector_type(8))) unsigned short u16x8;
typedef __attribute__((ext_vector_type(4))) unsigned short u16x4;
typedef __attribute__((ext_vector_type(4))) unsigned int u32x4;

__device__ inline unsigned short f2bf(float f) {
  unsigned u = __float_as_uint(f);
  return (unsigned short)((u + 0x7FFFu + ((u >> 16) & 1u)) >> 16);
}
__device__ inline float bf2f(unsigned short u) {
  return __uint_as_float(((unsigned)u) << 16);
}
__device__ inline unsigned short f2h(float f) {
  __half h = __float2half(f);
  return static_cast<__half_raw>(h).x;
}

// async global->LDS, 16B per lane; dest = wave-uniform base + lane*16
__device__ inline void gload16(const void* g, void* l) {
  __builtin_amdgcn_global_load_lds(
      (const __attribute__((address_space(1))) void*)g,
      (__attribute__((address_space(3))) void*)l, 16, 0, 0);
}

// ---------------------------------------------------------------------------
// prep_w: w [co][ci][3][3] f32 -> wT2 [9][co][ci] bf16 (B^T layout per shift).
// ---------------------------------------------------------------------------
__global__ __launch_bounds__(256) void prep_w(
    const float* __restrict__ w0, const float* __restrict__ w1,
    const float* __restrict__ w2, const float* __restrict__ w3,
    unsigned short* __restrict__ wT2, unsigned short* __restrict__ zp)
{
  int bx = blockIdx.x;
  int widx = bx >> 8;
  const float* src = (widx == 0) ? w0 : (widx == 1) ? w1 : (widx == 2) ? w2 : w3;
  int p = ((bx & 255) << 8) + threadIdx.x;          // p = co*256 + ci
  unsigned short* dst = wT2 + (size_t)widx * 589824;
  const float* s9 = src + (size_t)p * 9;
#pragma unroll
  for (int s = 0; s < 9; ++s) dst[(size_t)s * 65536 + p] = f2bf(s9[s]);
  if (bx == 0 && threadIdx.x < 128) zp[threadIdx.x] = 0;
}

// ---------------------------------------------------------------------------
// prep_x: x [B][C][H][W] f32 -> xT [B][N][C] bf16.
// ---------------------------------------------------------------------------
__global__ __launch_bounds__(256) void prep_x(
    const float* __restrict__ x, unsigned short* __restrict__ xT)
{
  __shared__ unsigned short T[64][72];
  int tid = threadIdx.x, bx = blockIdx.x;
  int b = bx >> 8, c0 = ((bx >> 6) & 3) * 64, n0 = (bx & 63) * 64;
#pragma unroll
  for (int it = 0; it < 16; ++it) {
    int c_l = (tid >> 6) + it * 4;
    int n_l = tid & 63;
    T[n_l][c_l] = f2bf(x[((size_t)(b * 256 + c0 + c_l)) * 4096 + n0 + n_l]);
  }
  __syncthreads();
#pragma unroll
  for (int it = 0; it < 8; ++it) {
    int n_l = (tid >> 5) + it * 8;
    int cp = (tid & 31) * 2;
    unsigned v = (unsigned)T[n_l][cp] | ((unsigned)T[n_l][cp + 1] << 16);
    *(unsigned*)&xT[((size_t)(b * 4096 + n0 + n_l)) * 256 + c0 + cp] = v;
  }
}

// ---------------------------------------------------------------------------
// conv_mfma: 3x3 SAME conv as 9 accumulated GEMMs, bf16 MFMA 16x16x32.
// Tile 128(M) x 64(N), grid 512.
// mode 0: fp16 [B][N][C]   mode 1: f32 [B][C][H][W]   mode 2: fp16 [B][C][N]
// ---------------------------------------------------------------------------
__global__ __launch_bounds__(256) void conv_mfma(
    const unsigned short* __restrict__ A,
    const unsigned short* __restrict__ W,
    const float* __restrict__ bias,
    void* __restrict__ out, int mode,
    const unsigned short* __restrict__ zp)
{
  __shared__ unsigned short As[2][128 * 64];   // 2 x 16KB
  __shared__ unsigned short Bs[2][64 * 64];    // 2 x 8KB

  const int tid = threadIdx.x;
  const int lane = tid & 63;
  const int w = tid >> 6;
  const int wr = w >> 1, wc = w & 1;
  const int nt = blockIdx.x & 3;
  const int mt = blockIdx.x >> 2;
  const int m0 = mt * 128;
  const int co0 = nt * 64;

  const int aslot = (lane & 7) ^ (lane >> 3);
  int gmj[4], yj[4], xj[4];
#pragma unroll
  for (int j = 0; j < 4; ++j) {
    int row = w * 32 + j * 8 + (lane >> 3);
    int gm = m0 + row;
    gmj[j] = gm;
    int n = gm & (NN - 1);
    yj[j] = n >> 6;
    xj[j] = n & 63;
  }
  int browj[2];
#pragma unroll
  for (int j = 0; j < 2; ++j)
    browj[j] = co0 + w * 16 + j * 8 + (lane >> 3);

  f32x4 acc[4][2];
#pragma unroll
  for (int mi = 0; mi < 4; ++mi)
#pragma unroll
    for (int ni = 0; ni < 2; ++ni) acc[mi][ni] = (f32x4){0.f, 0.f, 0.f, 0.f};

  auto stage = [&](int step, int sb) {
    int s = step >> 2, t = step & 3;
    int dy = s / 3 - 1, dx = s - (s / 3) * 3 - 1;
    const unsigned short* abase = A + t * 64 + aslot * 8;
    const unsigned short* wbase = W + ((size_t)s << 16) + t * 64 + aslot * 8;
#pragma unroll
    for (int j = 0; j < 4; ++j) {
      int yy = yj[j] + dy, xx = xj[j] + dx;
      bool valid = ((unsigned)yy < 64u) && ((unsigned)xx < 64u);
      const void* ga = valid
          ? (const void*)(abase + (size_t)(gmj[j] + dy * 64 + dx) * 256)
          : (const void*)zp;
      gload16(ga, (void*)&As[sb][(w * 4 + j) * 512]);
    }
#pragma unroll
    for (int j = 0; j < 2; ++j) {
      const void* gb = (const void*)(wbase + (size_t)browj[j] * 256);
      gload16(gb, (void*)&Bs[sb][(w * 2 + j) * 512]);
    }
  };

  const int r = lane & 15;
  const int klane = lane >> 4;
  const int rs = r & 7;

  int buf = 0;
  stage(0, 0);
  __syncthreads();
  for (int step = 0; step < 36; ++step) {
    if (step + 1 < 36) stage(step + 1, buf ^ 1);
    const unsigned short* as = As[buf];
    const unsigned short* bs = Bs[buf];
#pragma unroll
    for (int kk = 0; kk < 2; ++kk) {
      int slot = (kk * 4 + klane) ^ rs;
      bf16x8 a[4], bq[2];
#pragma unroll
      for (int mi = 0; mi < 4; ++mi)
        a[mi] = *(const bf16x8*)&as[(wr * 64 + mi * 16 + r) * 64 + slot * 8];
#pragma unroll
      for (int ni = 0; ni < 2; ++ni)
        bq[ni] = *(const bf16x8*)&bs[(wc * 32 + ni * 16 + r) * 64 + slot * 8];
#pragma unroll
      for (int mi = 0; mi < 4; ++mi)
#pragma unroll
        for (int ni = 0; ni < 2; ++ni)
          acc[mi][ni] = __builtin_amdgcn_mfma_f32_16x16x32_bf16(
              a[mi], bq[ni], acc[mi][ni], 0, 0, 0);
    }
    __syncthreads();
    buf ^= 1;
  }

  const int r4 = lane >> 4;
  const int colb = lane & 15;
  if (mode == 0) {
    unsigned short* o16 = (unsigned short*)out;
#pragma unroll
    for (int ni = 0; ni < 2; ++ni) {
      int co = co0 + wc * 32 + ni * 16 + colb;
      float bv = bias[co];
#pragma unroll
      for (int mi = 0; mi < 4; ++mi) {
        int gm0 = m0 + wr * 64 + mi * 16 + r4 * 4;
#pragma unroll
        for (int rr = 0; rr < 4; ++rr) {
          float v = fmaxf(acc[mi][ni][rr] + bv, 0.f);
          o16[(size_t)(gm0 + rr) * 256 + co] = f2h(v);
        }
      }
    }
  } else if (mode == 1) {
    float* o32 = (float*)out;
#pragma unroll
    for (int ni = 0; ni < 2; ++ni) {
      int co = co0 + wc * 32 + ni * 16 + colb;
      float bv = bias[co];
#pragma unroll
      for (int mi = 0; mi < 4; ++mi) {
        int gm0 = m0 + wr * 64 + mi * 16 + r4 * 4;
#pragma unroll
        for (int rr = 0; rr < 4; ++rr) {
          float v = fmaxf(acc[mi][ni][rr] + bv, 0.f);
          int gm = gm0 + rr;
          int b = gm >> 12, n = gm & (NN - 1);
          o32[((size_t)(b * 256 + co)) * 4096 + n] = v;
        }
      }
    }
  } else {
    unsigned short* o16 = (unsigned short*)out;
#pragma unroll
    for (int ni = 0; ni < 2; ++ni) {
      int co = co0 + wc * 32 + ni * 16 + colb;
      float bv = bias[co];
#pragma unroll
      for (int mi = 0; mi < 4; ++mi) {
        int gm0 = m0 + wr * 64 + mi * 16 + r4 * 4;
#pragma unroll
        for (int rr = 0; rr < 4; ++rr) {
          float v = fmaxf(acc[mi][ni][rr] + bv, 0.f);
          int gm = gm0 + rr;
          int b = gm >> 12, n = gm & (NN - 1);
          o16[((size_t)(b * 256 + co)) * 4096 + n] = f2h(v);
        }
      }
    }
  }
}

// ---------------------------------------------------------------------------
// MFMA flash attention v3: 2-way key-split across blocks for 2 blocks/CU
// (8 waves/CU), KVBLK=32, defer-rescale (THR=8), setprio around MFMA.
// Block = (half, b, qtile): keys half*2048..+2048, 64 queries.
// Emits UNNORMALIZED partial O^T (bf16) + (m, l) per query to workspace.
// ---------------------------------------------------------------------------
__global__ __launch_bounds__(256, 2) void attn_k(
    const unsigned short* __restrict__ qT, const unsigned short* __restrict__ kT,
    const unsigned short* __restrict__ vTc,
    unsigned short* __restrict__ pO, float2* __restrict__ pml)
{
  __shared__ unsigned short Ks[2][32 * 256];   // 2 x 16KB, [key][c], swizzled
  __shared__ unsigned short Vts[2][256 * 32];  // 2 x 16KB, [c][key], swizzled

  const int tid = threadIdx.x;
  const int lane = tid & 63;
  const int w = tid >> 6;
  const int wq = w >> 1, wc = w & 1;
  const int hi = lane >> 5;
  const int la = lane & 31;
  const int a7 = la & 7;
  const int bx = blockIdx.x;
  const int half = bx >> 8;
  const int b = (bx >> 6) & 3;
  const int q0 = (bx & 63) << 6;
  const int kbase = half << 11;

  // ---- Q as B-fragments: qf[ks] = Q[q0+32wq+la][16ks+8hi .. +8] ----
  f16x8 qf[16];
  {
    const unsigned short* qp =
        qT + ((size_t)(b * NN) + q0 + 32 * wq + la) * CC + 8 * hi;
#pragma unroll
    for (int ks = 0; ks < 16; ++ks)
      qf[ks] = *(const f16x8*)(qp + ks * 16);
  }

  const unsigned short* kTb = kT + (size_t)b * NN * CC;
  const unsigned short* vTb = vTc + (size_t)b * CC * NN;
  auto stageKV = [&](int t, int sb) {
    int k0 = kbase + (t << 5);
    {  // K: [32 rows][256 c]; wave stages rows 8w..8w+7 (4 x 1KB)
      int row_l = lane >> 5;
      int slot = lane & 31;
#pragma unroll
      for (int i = 0; i < 4; ++i) {
        int row = 8 * w + i * 2 + row_l;
        const void* src = (const void*)(kTb + (size_t)(k0 + row) * CC +
                                        ((slot ^ (row & 7)) << 3));
        gload16(src, (void*)&Ks[sb][(8 * w + i * 2) * 256]);
      }
    }
    {  // Vt: [256 c][32 k]; wave stages channels 64w..64w+63 (4 x 1KB)
      int c_l = lane >> 2;
      int sp = lane & 3;
#pragma unroll
      for (int i = 0; i < 4; ++i) {
        int c = 64 * w + 16 * i + c_l;
        const void* src = (const void*)(vTb + (size_t)c * NN + k0 +
                                        ((sp ^ ((c >> 2) & 3)) << 3));
        gload16(src, (void*)&Vts[sb][(64 * w + 16 * i) * 32]);
      }
    }
  };

  float mprev = -INFINITY, lsum = 0.f;
  f32x16 O[4];
#pragma unroll
  for (int nc = 0; nc < 4; ++nc)
#pragma unroll
    for (int rr = 0; rr < 16; ++rr) O[nc][rr] = 0.f;

  stageKV(0, 0);
  __syncthreads();

  int buf = 0;
  for (int t = 0; t < 64; ++t) {
    if (t + 1 < 64) stageKV(t + 1, buf ^ 1);

    // ---- QK^T (swapped): S^T[32 keys][32 q] ----
    f32x16 S0;
#pragma unroll
    for (int rr = 0; rr < 16; ++rr) S0[rr] = 0.f;
    const unsigned short* ks_ = Ks[buf];
    __builtin_amdgcn_s_setprio(1);
#pragma unroll
    for (int ks = 0; ks < 16; ++ks) {
      f16x8 a0 = *(const f16x8*)&ks_[la * 256 + ((((ks << 1) + hi) ^ a7) << 3)];
      S0 = __builtin_amdgcn_mfma_f32_32x32x16_f16(a0, qf[ks], S0, 0, 0, 0);
    }
    __builtin_amdgcn_s_setprio(0);

    // ---- online softmax, defer-rescale (THR=8) ----
    float mloc = S0[0];
#pragma unroll
    for (int rr = 1; rr < 16; ++rr) mloc = fmaxf(mloc, S0[rr]);
    {
      auto sw = __builtin_amdgcn_permlane32_swap(
          __float_as_uint(mloc), __float_as_uint(mloc), false, false);
      mloc = fmaxf(__uint_as_float(sw[0]), __uint_as_float(sw[1]));
    }
    if (!__all(mloc <= mprev + 8.f)) {
      float mnew = fmaxf(mprev, mloc);
      float sc = __expf(mprev - mnew);   // exp(-inf)=0 on first chunk
      lsum *= sc;
#pragma unroll
      for (int nc = 0; nc < 4; ++nc)
#pragma unroll
        for (int rr = 0; rr < 16; ++rr) O[nc][rr] *= sc;
      mprev = mnew;
    }
    float rsm = 0.f;
#pragma unroll
    for (int rr = 0; rr < 16; ++rr) {
      S0[rr] = __expf(S0[rr] - mprev);
      rsm += S0[rr];
    }
    {
      auto sw = __builtin_amdgcn_permlane32_swap(
          __float_as_uint(rsm), __float_as_uint(rsm), false, false);
      rsm = __uint_as_float(sw[0]) + __uint_as_float(sw[1]);
    }
    lsum += rsm;

    // ---- pack P to fp16 A-row-fragments (cvt_pkrtz + permlane32_swap) ----
    f16x8 pf[2];
#pragma unroll
    for (int kk = 0; kk < 2; ++kk) {
      const int r0 = kk * 8;
      unsigned w0 = __builtin_bit_cast(unsigned,
          __builtin_amdgcn_cvt_pkrtz(S0[r0 + 0], S0[r0 + 1]));
      unsigned w1 = __builtin_bit_cast(unsigned,
          __builtin_amdgcn_cvt_pkrtz(S0[r0 + 2], S0[r0 + 3]));
      unsigned w2 = __builtin_bit_cast(unsigned,
          __builtin_amdgcn_cvt_pkrtz(S0[r0 + 4], S0[r0 + 5]));
      unsigned w3 = __builtin_bit_cast(unsigned,
          __builtin_amdgcn_cvt_pkrtz(S0[r0 + 6], S0[r0 + 7]));
      auto sA = __builtin_amdgcn_permlane32_swap(w0, w2, false, false);
      auto sB = __builtin_amdgcn_permlane32_swap(w1, w3, false, false);
      u32x4 fw;
      fw[0] = sA[0]; fw[1] = sB[0]; fw[2] = sA[1]; fw[3] = sB[1];
      pf[kk] = __builtin_bit_cast(f16x8, fw);
    }

    // ---- PV: O^T[c][q] += Vt-frag x P-frag ----
    const unsigned short* vs_ = Vts[buf];
    __builtin_amdgcn_s_setprio(1);
#pragma unroll
    for (int kk = 0; kk < 2; ++kk) {
#pragma unroll
      for (int nc = 0; nc < 4; ++nc) {
        int c = 128 * wc + 32 * nc + la;
        f16x8 vf = *(const f16x8*)&vs_[c * 32 +
                                       ((((kk << 1) + hi) ^ ((c >> 2) & 3)) << 3)];
        O[nc] = __builtin_amdgcn_mfma_f32_32x32x16_f16(vf, pf[kk], O[nc], 0, 0, 0);
      }
    }
    __builtin_amdgcn_s_setprio(0);

    __syncthreads();
    buf ^= 1;
  }

  // ---- epilogue: unnormalized partial O^T (bf16) + (m,l) ----
  {
    int n = q0 + 32 * wq + la;
    unsigned short* dst = pO + (((size_t)(half * 4 + b)) * NN + n) * CC;
#pragma unroll
    for (int nc = 0; nc < 4; ++nc) {
#pragma unroll
      for (int tq = 0; tq < 4; ++tq) {
        int c0 = 128 * wc + 32 * nc + 8 * tq + 4 * hi;
        u16x4 pk;
        pk[0] = f2bf(O[nc][4 * tq + 0]);
        pk[1] = f2bf(O[nc][4 * tq + 1]);
        pk[2] = f2bf(O[nc][4 * tq + 2]);
        pk[3] = f2bf(O[nc][4 * tq + 3]);
        *(u16x4*)&dst[c0] = pk;
      }
    }
    if (wc == 0 && hi == 0)
      pml[(size_t)half * 4 * NN + (size_t)b * NN + n] =
          make_float2(mprev, lsum);
  }
}

// ---------------------------------------------------------------------------
// combine_k: merge the two key-half partials -> ctx bf16 [B][N][C] (x2).
// ---------------------------------------------------------------------------
__global__ __launch_bounds__(256) void combine_k(
    const unsigned short* __restrict__ pO, const float2* __restrict__ pml,
    unsigned short* __restrict__ ctx)
{
  int bx = blockIdx.x;
  int b = bx >> 6;
  int q = ((bx & 63) << 6) + (threadIdx.x >> 2);
  int c0 = (threadIdx.x & 3) << 6;
  size_t nidx = (size_t)b * NN + q;
  float2 ml0 = pml[nidx];
  float2 ml1 = pml[(size_t)4 * NN + nidx];
  float m = fmaxf(ml0.x, ml1.x);
  float w0 = __expf(ml0.x - m), w1 = __expf(ml1.x - m);
  float inv = 2.f / (ml0.y * w0 + ml1.y * w1);
  const unsigned short* p0 = pO + nidx * CC + c0;
  const unsigned short* p1 = pO + (size_t)4 * NN * CC + nidx * CC + c0;
  unsigned short* d = ctx + nidx * CC + c0;
#pragma unroll
  for (int j = 0; j < 8; ++j) {
    u16x8 a = *(const u16x8*)(p0 + j * 8);
    u16x8 bb = *(const u16x8*)(p1 + j * 8);
    u16x8 o;
#pragma unroll
    for (int e = 0; e < 8; ++e)
      o[e] = f2bf((bf2f(a[e]) * w0 + bf2f(bb[e]) * w1) * inv);
    *(u16x8*)(d + j * 8) = o;
  }
}

extern "C" void kernel_launch(void* const* d_in, const int* in_sizes, int n_in,
                              void* d_out, int out_size, void* d_ws, size_t ws_size,
                              hipStream_t stream) {
  const float* x  = (const float*)d_in[0];
  const float* wq = (const float*)d_in[1];
  const float* bq = (const float*)d_in[2];
  const float* wk = (const float*)d_in[3];
  const float* bk = (const float*)d_in[4];
  const float* wv = (const float*)d_in[5];
  const float* bv = (const float*)d_in[6];
  const float* wo = (const float*)d_in[7];
  const float* bo = (const float*)d_in[8];

  char* ws = (char*)d_ws;
  unsigned short* xT  = (unsigned short*)(ws);              // bf16 [B][N][C]
  unsigned short* wT2 = (unsigned short*)(ws + 8388608);    // bf16 [4][9][co][ci]
  unsigned short* qT  = (unsigned short*)(ws + 13107200);   // fp16 [B][N][C]
  unsigned short* kT  = (unsigned short*)(ws + 21495808);   // fp16 [B][N][C]
  unsigned short* vTc = (unsigned short*)(ws + 29884416);   // fp16 [B][C][N]
  unsigned short* ctx = (unsigned short*)(ws + 38273024);   // bf16 [B][N][C]
  unsigned short* zp  = (unsigned short*)(ws + 46661632);   // 512 B zeros
  unsigned short* pO  = (unsigned short*)(ws + 46662144);   // bf16 [2][B][N][C] 16MB
  float2*         pml = (float2*)(ws + 63439360);           // f32x2 [2][B][N] 256KB

  prep_w<<<dim3(1024), 256, 0, stream>>>(wq, wk, wv, wo, wT2, zp);
  prep_x<<<dim3(1024), 256, 0, stream>>>(x, xT);
  conv_mfma<<<dim3(512), 256, 0, stream>>>(xT, wT2,               bq, qT, 0, zp);
  conv_mfma<<<dim3(512), 256, 0, stream>>>(xT, wT2 + 589824,      bk, kT, 0, zp);
  conv_mfma<<<dim3(512), 256, 0, stream>>>(xT, wT2 + 2 * 589824,  bv, vTc, 2, zp);
  attn_k<<<dim3(512), 256, 0, stream>>>(qT, kT, vTc, pO, pml);
  combine_k<<<dim3(256), 256, 0, stream>>>(pO, pml, ctx);
  conv_mfma<<<dim3(512), 256, 0, stream>>>(ctx, wT2 + 3 * 589824, bo, (float*)d_out, 1, zp);
}